// Round 1
// baseline (226.077 us; speedup 1.0000x reference)
//
#include <hip/hip_runtime.h>

// Correlation / cost-volume layer, fp32.
// corr[b, dy*9+dx, y, x] = (1/C) * sum_c in1[b,c,y,x] * in2[b,c,y+dy-4,x+dx-4]
// (zero-padded outside the image).
//
// Strategy: block = (b, 4-row y-quad). 576 threads = (ly:4, dy:9, xg:16).
// Each thread: one dy, all 9 dx, 8 x-pixels (two float4 quads at x0, x0+64)
// -> 72 accumulators. Channel loop in chunks of 8; in2 rows staged in LDS
// (padded by 4 on each side in x; out-of-range y rows zeroed once), in1 read
// directly from global (L1 serves the 9x dy-redundancy).
// Per channel per thread: 6 LDS float4 + 2 global float4 feed 72 FMAs
// -> VALU-bound by design (144 cyc FMA vs ~72 cyc LDS per wave-channel).

#define MAXD 4
#define ND 9
#define NDISP 81
#define BATCH 8
#define CH 128
#define HH 128
#define WW 128
#define CC 8
#define NCHUNK (CH / CC)
#define TY 4
#define NROW (TY + 2 * MAXD)   // 12 in2 rows per block
#define P2 136                 // padded in2 row: p = x + 4, p in [0,136)
#define NT 576                 // 4 * 9 * 16 threads = 9 waves

__global__ __launch_bounds__(NT) void corr_kernel(
    const float* __restrict__ in1,
    const float* __restrict__ in2,
    float* __restrict__ out)
{
    __shared__ float s2[NROW * CC * P2];   // 12*8*136 floats = 51 KB

    const int tid = threadIdx.x;
    const int b  = blockIdx.x;
    const int y0 = blockIdx.y * TY;

    // ---- one-time zero init of constant-zero LDS regions ----
    // pad columns: p in [0,4) and [132,136) for every (row, c)
    for (int j = tid; j < NROW * CC * 8; j += NT) {
        int row = j / (CC * 8);
        int rem = j - row * (CC * 8);
        int c  = rem >> 3;
        int pp = rem & 7;
        int p  = (pp < 4) ? pp : (WW + pp);   // 0..3 or 132..135
        s2[(row * CC + c) * P2 + p] = 0.0f;
    }
    // out-of-range y rows: whole row zero (stays zero; staging skips them)
    for (int row = 0; row < NROW; ++row) {
        int r = y0 + row - MAXD;
        if (r < 0 || r >= HH) {
            for (int j = tid; j < CC * WW; j += NT) {
                int c = j >> 7;
                int x = j & 127;
                s2[(row * CC + c) * P2 + 4 + x] = 0.0f;
            }
        }
    }

    // ---- compute-thread mapping ----
    const int ly = tid / (ND * 16);     // 0..3  output row within quad
    const int dy = (tid / 16) % ND;     // 0..8  displacement row
    const int xg = tid & 15;            // 0..15 x-group
    const int x0 = xg * 4;              // first quad: x0..x0+3; second: +64
    const int rl = ly + dy;             // LDS row index (r = y0+ly+dy-4)

    float acc0[ND][4], acc1[ND][4];
    #pragma unroll
    for (int d = 0; d < ND; ++d)
        #pragma unroll
        for (int i = 0; i < 4; ++i) { acc0[d][i] = 0.0f; acc1[d][i] = 0.0f; }

    const float* in2b   = in2 + (size_t)b * CH * HH * WW;
    const float* in1row = in1 + (size_t)b * CH * HH * WW + (size_t)(y0 + ly) * WW;

    for (int ch = 0; ch < NCHUNK; ++ch) {
        const int c0 = ch * CC;
        __syncthreads();   // previous compute done (and zero-init on ch==0)

        // ---- stage in2 chunk: 12 rows x 8 ch x 32 float4 ----
        for (int j = tid; j < NROW * CC * 32; j += NT) {
            int row = j >> 8;            // / (8*32)
            int c   = (j >> 5) & 7;
            int xq  = j & 31;
            int r   = y0 + row - MAXD;
            if (r >= 0 && r < HH) {
                float4 v = *(const float4*)(in2b + ((size_t)(c0 + c) * HH + r) * WW + xq * 4);
                *(float4*)&s2[(row * CC + c) * P2 + 4 + xq * 4] = v;
            }
        }
        __syncthreads();

        // ---- accumulate 8 channels ----
        #pragma unroll
        for (int c = 0; c < CC; ++c) {
            const float* s2r = &s2[(rl * CC + c) * P2];
            float4 b0a = *(const float4*)(s2r + x0);
            float4 b0b = *(const float4*)(s2r + x0 + 4);
            float4 b0c = *(const float4*)(s2r + x0 + 8);
            float4 b1a = *(const float4*)(s2r + x0 + 64);
            float4 b1b = *(const float4*)(s2r + x0 + 68);
            float4 b1c = *(const float4*)(s2r + x0 + 72);
            float bb0[12] = {b0a.x, b0a.y, b0a.z, b0a.w,
                             b0b.x, b0b.y, b0b.z, b0b.w,
                             b0c.x, b0c.y, b0c.z, b0c.w};
            float bb1[12] = {b1a.x, b1a.y, b1a.z, b1a.w,
                             b1b.x, b1b.y, b1b.z, b1b.w,
                             b1c.x, b1c.y, b1c.z, b1c.w};

            const float* p1 = in1row + (size_t)(c0 + c) * HH * WW;
            float4 a0 = *(const float4*)(p1 + x0);
            float4 a1 = *(const float4*)(p1 + x0 + 64);
            float aa0[4] = {a0.x, a0.y, a0.z, a0.w};
            float aa1[4] = {a1.x, a1.y, a1.z, a1.w};

            #pragma unroll
            for (int d = 0; d < ND; ++d) {
                #pragma unroll
                for (int i = 0; i < 4; ++i) {
                    acc0[d][i] = fmaf(aa0[i], bb0[i + d], acc0[d][i]);
                    acc1[d][i] = fmaf(aa1[i], bb1[i + d], acc1[d][i]);
                }
            }
        }
    }

    // ---- epilogue: mean over C, coalesced float4 stores ----
    const float scale = 1.0f / (float)CH;
    float* outb = out + (size_t)b * NDISP * HH * WW + (size_t)(y0 + ly) * WW;
    #pragma unroll
    for (int d = 0; d < ND; ++d) {
        float* op = outb + (size_t)(dy * ND + d) * HH * WW;
        float4 v0 = make_float4(acc0[d][0] * scale, acc0[d][1] * scale,
                                acc0[d][2] * scale, acc0[d][3] * scale);
        float4 v1 = make_float4(acc1[d][0] * scale, acc1[d][1] * scale,
                                acc1[d][2] * scale, acc1[d][3] * scale);
        *(float4*)(op + x0)      = v0;
        *(float4*)(op + x0 + 64) = v1;
    }
}

extern "C" void kernel_launch(void* const* d_in, const int* in_sizes, int n_in,
                              void* d_out, int out_size, void* d_ws, size_t ws_size,
                              hipStream_t stream) {
    const float* in1 = (const float*)d_in[0];
    const float* in2 = (const float*)d_in[1];
    float* out = (float*)d_out;
    dim3 grid(BATCH, HH / TY);
    corr_kernel<<<grid, NT, 0, stream>>>(in1, in2, out);
}